// Round 6
// baseline (2598.745 us; speedup 1.0000x reference)
//
#include <hip/hip_runtime.h>
#include <hip/hip_bf16.h>
#include <stdint.h>

typedef __attribute__((ext_vector_type(8))) short short8;
typedef __attribute__((ext_vector_type(4))) float f32x4;

#define B_ 32
#define N_ 196
#define D_ 1024
#define V_ 32000
#define NSTEP 99
#define MROWS 3168   // 99*32
#define MPAD  3200

// workspace layout (bytes)
#define OFF_WT    0ULL          // bf16 [32000][1024]  = 65,536,000 B
#define OFF_H     65536000ULL   // bf16 [3200][1024]   =  6,553,600 B
#define OFF_FSUM  72089600ULL   // f32  [32][1024]     (dead after k_ctx)
#define OFF_CTX   72220672ULL   // f32  [32][1024]     (dead after k_gbase)
#define OFF_EX    72089600ULL   // u64  [2][16384]     = 262,144 B (aliases FSUM+CTX; memset after k_gbase)
#define OFF_GBASE 72351744ULL   // f32  [32][4096]     = 524,288 B

#define AS3 __attribute__((address_space(3)))
#define AS1 __attribute__((address_space(1)))
static __device__ __forceinline__ void gload_lds16(const void* g, void* l) {
  __builtin_amdgcn_global_load_lds((const AS1 uint32_t*)g, (AS3 uint32_t*)l, 16, 0, 0);
}

// ---------------- out[0] one-hot + zero H pad rows ----------------
__global__ void k_first(float* __restrict__ out, __hip_bfloat16* __restrict__ H) {
  int idx = blockIdx.x * 256 + threadIdx.x;           // 0 .. 1,024,000
  if (idx < B_ * V_) out[idx] = ((idx % V_) == 0) ? 1.0f : 0.0f;
  if (idx < 16384) ((uint32_t*)(H + (size_t)MROWS * D_))[idx] = 0u;  // rows 3168..3199
}

// ---------------- fsum[b,e] = sum_n relu(features[b,n,e]) ----------------
__global__ void k_fsum(const float* __restrict__ feat, float* __restrict__ fsum) {
  int idx = blockIdx.x * 256 + threadIdx.x;           // 32768
  int b = idx >> 10, e = idx & 1023;
  const float* p = feat + (size_t)b * (N_ * D_) + e;
  float s = 0.f;
  #pragma unroll 4
  for (int n = 0; n < N_; ++n) s += fmaxf(p[(size_t)n * D_], 0.f);
  fsum[idx] = s;
}

// ---------------- ctx[b,d] = fsum[b,:] @ W_fv[:,d] + 196*b_fv[d] ----------------
__global__ void k_ctx(const float* __restrict__ fsum, const float* __restrict__ W_fv,
                      const float* __restrict__ b_fv, float* __restrict__ ctx) {
  __shared__ float fs[1024];
  int b = blockIdx.y;
  int d = blockIdx.x * 256 + threadIdx.x;             // grid.x = 4
  for (int i = threadIdx.x; i < 1024; i += 256) fs[i] = fsum[b * 1024 + i];
  __syncthreads();
  float s = 196.f * b_fv[d];
  #pragma unroll 4
  for (int e = 0; e < 1024; ++e) s = fmaf(fs[e], W_fv[(size_t)e * 1024 + d], s);
  ctx[b * 1024 + d] = s;
}

// ---------------- gbase[b,j] = ctx[b,:] @ W_ih[:,j] + b_ih[j] + b_hh[j] ----------------
__global__ void k_gbase(const float* __restrict__ ctx, const float* __restrict__ W_ih,
                        const float* __restrict__ b_ih, const float* __restrict__ b_hh,
                        float* __restrict__ gbase) {
  __shared__ float cs[8][1024];
  int j = blockIdx.x * 256 + threadIdx.x;             // grid.x = 16 -> 0..4095
  int b0 = blockIdx.y * 8;                            // grid.y = 4
  for (int i = threadIdx.x; i < 8 * 1024; i += 256)
    cs[i >> 10][i & 1023] = ctx[(size_t)(b0 + (i >> 10)) * 1024 + (i & 1023)];
  __syncthreads();
  float bias = b_ih[j] + b_hh[j];
  float acc[8];
  #pragma unroll
  for (int r = 0; r < 8; ++r) acc[r] = bias;
  for (int e = 0; e < 1024; ++e) {
    float w = W_ih[(size_t)e * 4096 + j];
    #pragma unroll
    for (int r = 0; r < 8; ++r) acc[r] = fmaf(cs[r][e], w, acc[r]);
  }
  #pragma unroll
  for (int r = 0; r < 8; ++r) gbase[(size_t)(b0 + r) * 4096 + j] = acc[r];
}

// ---------------- W_lm [1024][32000] f32 -> WT [32000][1024] bf16 (vectorized stores) ----------------
__global__ void k_convT(const float* __restrict__ W, __hip_bfloat16* __restrict__ WT) {
  __shared__ __hip_bfloat16 t[64][66];
  int k0 = blockIdx.x * 64;                           // grid.x = 16
  int n0 = blockIdx.y * 64;                           // grid.y = 500
  int tx = threadIdx.x & 63, ty = threadIdx.x >> 6;   // 256 threads, 4 waves
  #pragma unroll
  for (int i = 0; i < 16; ++i) {
    int r = i * 4 + ty;
    t[r][tx] = __float2bfloat16(W[(size_t)(k0 + r) * V_ + n0 + tx]);
  }
  __syncthreads();
  // store: each WT row (64 k) = 32 u32 words; lane&31 -> word (packs k=2w,2w+1),
  // lane>>5 + 2*wave -> n-row; 8 iters x 4 waves x 2 rows = 64 rows.
  int word = tx & 31;
  int nh = tx >> 5;
  #pragma unroll
  for (int i = 0; i < 8; ++i) {
    int n = i * 8 + ty * 2 + nh;
    uint32_t lo = *(const uint16_t*)&t[2 * word][n];
    uint32_t hi = *(const uint16_t*)&t[2 * word + 1][n];
    ((uint32_t*)&WT[(size_t)(n0 + n) * 1024 + k0])[word] = lo | (hi << 16);
  }
}

// ---------------- persistent LSTM recurrence: 32 blocks x 1024 threads, 99 steps ----------------
// Each block owns 32 h-dims (128 gate cols); W_hh slice lives in 128 VGPR/thread (breg).
// Fence-free exchange: h-pairs published as tagged u64 relaxed AGENT atomics
// (tag = t+1 | 2x bf16). Parity double-buffer; consumers poll 16 words/thread.
__global__ __launch_bounds__(1024, 1) void k_rec(
    const float* __restrict__ gbase, const float* __restrict__ W_hh,
    const float* __restrict__ bos, __hip_bfloat16* __restrict__ H,
    unsigned long long* __restrict__ Ex) {
  extern __shared__ char lds[];
  __hip_bfloat16* hbuf = (__hip_bfloat16*)lds;             // [32][1024] bf16 swizzled (64KB)
  __hip_bfloat16* temp = (__hip_bfloat16*)(lds + 65536);   // [32 cols][1024] bf16 swizzled (64KB, init only)
  float* gex = (float*)(lds + 131072);                     // [32][132] f32 (16.9KB)

  const int tid = threadIdx.x;
  const int blk = blockIdx.x;      // 0..31
  const int d0 = blk * 32;

  const int lane = tid & 63;
  const int wid = tid >> 6;        // 0..15
  const int bt = wid >> 3;         // batch-tile 0..1
  const int ct = wid & 7;          // col-tile 0..7  (cols ct*16..+16 of 128)
  const int arow = bt * 16 + (lane & 15);
  const int kg = lane >> 4;
  const int axor = arow & 7;

  // h0 = bos broadcast to all batches
  for (int idx = tid; idx < 32 * 1024; idx += 1024) {
    int row = idx >> 10;
    int k = idx & 1023;
    hbuf[row * 1024 + ((((k >> 3) ^ (row & 7)) << 3) | (k & 7))] = __float2bfloat16(bos[k]);
  }

  // W_hh slice -> breg, 4 staging rounds (round r = gate r; cols r*32..r*32+31)
  short8 breg[32];
  const int bcl = (ct & 1) * 16 + (lane & 15);   // col_local in [0,32)
  const int bxorw = bcl & 7;
  for (int r = 0; r < 4; ++r) {
    __syncthreads();                             // prev extraction done / temp free
    for (int i = tid; i < 32 * 1024; i += 1024) {
      int c = i & 31;
      int k = i >> 5;
      float w = W_hh[(size_t)k * 4096 + r * 1024 + d0 + c];
      temp[c * 1024 + ((((k >> 3) ^ (c & 7)) << 3) | (k & 7))] = __float2bfloat16(w);
    }
    __syncthreads();
    if ((ct >> 1) == r) {
      #pragma unroll
      for (int kt = 0; kt < 32; ++kt) {
        int ca = kt * 4 + kg;
        breg[kt] = *(const short8*)&temp[bcl * 1024 + ((ca ^ bxorw) << 3)];
      }
    }
  }

  // gate-compute constants: thread -> (batch tb, local dim tdl)
  const int tb = tid >> 5;      // 0..31
  const int tdl = tid & 31;     // 0..31
  float gb0 = gbase[(size_t)tb * 4096 + 0 * 1024 + d0 + tdl];
  float gb1 = gbase[(size_t)tb * 4096 + 1 * 1024 + d0 + tdl];
  float gb2 = gbase[(size_t)tb * 4096 + 2 * 1024 + d0 + tdl];
  float gb3 = gbase[(size_t)tb * 4096 + 3 * 1024 + d0 + tdl];
  float cst = 0.f;

  // consumer constants: thread handles words w = j*1024 + tid, j=0..15
  const int ctb = (tid & 511) >> 4;   // deposit batch
  const int cpr = tid & 15;           // pair index within 32-dim slice
  const int coff2 = (cpr & 3) * 2;    // elem offset within 8-elem chunk
  const int cxor = ctb & 7;
  const int chalf = tid >> 9;         // 0/1: src block parity

  __syncthreads();

  for (int t = 0; t < NSTEP; ++t) {
    // gates[32 batches x 128 cols] = h @ Wslice  (16 waves x 32 MFMA, B in regs)
    f32x4 acc0 = {0.f, 0.f, 0.f, 0.f};
    f32x4 acc1 = {0.f, 0.f, 0.f, 0.f};
    #pragma unroll
    for (int kt = 0; kt < 32; kt += 2) {
      int ca = kt * 4 + kg;
      short8 a0 = *(const short8*)&hbuf[arow * 1024 + ((ca ^ axor) << 3)];
      acc0 = __builtin_amdgcn_mfma_f32_16x16x32_bf16(a0, breg[kt], acc0, 0, 0, 0);
      short8 a1 = *(const short8*)&hbuf[arow * 1024 + (((ca + 4) ^ axor) << 3)];
      acc1 = __builtin_amdgcn_mfma_f32_16x16x32_bf16(a1, breg[kt + 1], acc1, 0, 0, 0);
    }
    acc0 = acc0 + acc1;
    {
      int bq = bt * 16 + ((lane >> 4) << 2);
      int col = ct * 16 + (lane & 15);
      #pragma unroll
      for (int q = 0; q < 4; ++q) gex[(bq + q) * 132 + col] = acc0[q];
    }
    __syncthreads();   // S1: gex written; hbuf reads of step t complete

    float gi = gex[tb * 132 + 0  + tdl] + gb0;
    float gf = gex[tb * 132 + 32 + tdl] + gb1;
    float gg = gex[tb * 132 + 64 + tdl] + gb2;
    float go = gex[tb * 132 + 96 + tdl] + gb3;
    float si = 1.f / (1.f + __expf(-gi));
    float sf = 1.f / (1.f + __expf(-gf));
    float so = 1.f / (1.f + __expf(-go));
    cst = sf * cst + si * tanhf(gg);
    float h = so * tanhf(cst);
    H[(size_t)t * (B_ * D_) + tb * D_ + d0 + tdl] = __float2bfloat16(h);

    // publish h-pair as tagged u64 (fence-free, relaxed agent atomic)
    float hother = __shfl_xor(h, 1);
    if (t < NSTEP - 1 && (tdl & 1) == 0) {
      __hip_bfloat16 p0 = __float2bfloat16(h);
      __hip_bfloat16 p1 = __float2bfloat16(hother);
      uint32_t pk = (uint32_t)*(uint16_t*)&p0 | ((uint32_t)*(uint16_t*)&p1 << 16);
      unsigned long long v = ((unsigned long long)(unsigned)(t + 1) << 32) | pk;
      unsigned long long* dst = Ex + ((t & 1) ? 16384 : 0) + blk * 512 + tb * 16 + (tdl >> 1);
      __hip_atomic_store(dst, v, __ATOMIC_RELAXED, __HIP_MEMORY_SCOPE_AGENT);
    }

    if (t == NSTEP - 1) break;

    // poll 16 words/thread, idempotent deposit into hbuf
    {
      const unsigned long long want = (unsigned long long)(unsigned)(t + 1);
      const unsigned long long* ExB = Ex + ((t & 1) ? 16384 : 0);
      for (;;) {
        unsigned long long v[16];
        #pragma unroll
        for (int j = 0; j < 16; ++j)
          v[j] = __hip_atomic_load(&ExB[j * 1024 + tid],
                                   __ATOMIC_RELAXED, __HIP_MEMORY_SCOPE_AGENT);
        int nready = 0;
        #pragma unroll
        for (int j = 0; j < 16; ++j) {
          if ((v[j] >> 32) == want) {
            int src = 2 * j + chalf;               // source block 0..31
            int ch = src * 4 + (cpr >> 2);         // 8-elem chunk index
            *(uint32_t*)&hbuf[ctb * 1024 + ((ch ^ cxor) << 3) + coff2] = (uint32_t)v[j];
            ++nready;
          }
        }
        if (nready == 16) break;
        __builtin_amdgcn_s_sleep(2);
      }
    }
    __syncthreads();   // S2: hbuf fully deposited
  }
}

// ---------------- logits GEMM: 256x256 tiles, 8 waves, global_load_lds staging ----------------
// [3168(+pad),1024] x [1024,32000]; grouped raster (GM=4, mt fastest) for L2 locality.
__global__ __launch_bounds__(512, 2) void k_gemm(
    const __hip_bfloat16* __restrict__ H,    // [3200][1024] (rows 3168..3199 zero)
    const __hip_bfloat16* __restrict__ WT,   // [32000][1024]
    const float* __restrict__ b_lm,
    float* __restrict__ out) {
  __shared__ __hip_bfloat16 As[256 * 64];    // 32 KB
  __shared__ __hip_bfloat16 Bs[256 * 64];    // 32 KB

  // XCD-bijective remap: nwg = 1625 = 8*203 + 1
  int bid = blockIdx.x;
  int xcd = bid & 7;
  int idx = bid >> 3;
  int wg = (xcd < 1 ? xcd * 204 : 204 + (xcd - 1) * 203) + idx;
  // grouped raster: groups of GM=4 m-tiles, mt fastest within group (13 = 4+4+4+1)
  int group = wg / 500;                       // 0..3
  int u = wg - group * 500;
  int gm = (group == 3) ? 1 : 4;
  int mt = group * 4 + (u % gm);              // 0..12
  int nt = u / gm;                            // 0..124
  const int mbase = mt * 256;
  const int nbase = nt * 256;

  const int tid = threadIdx.x;
  const int lane = tid & 63;
  const int wid = tid >> 6;      // 0..7
  const int wm = wid >> 2;       // 0..1  (M 128-half)
  const int wn = wid & 3;        // 0..3  (N 64-quarter)

  f32x4 acc[8][4];
  #pragma unroll
  for (int m = 0; m < 8; ++m)
    #pragma unroll
    for (int n = 0; n < 4; ++n) acc[m][n] = (f32x4){0.f, 0.f, 0.f, 0.f};

  const int kg = lane >> 4;

  // staging constants: chunk c = j*512 + tid; row = c>>3; slot = c&7;
  // source slot pre-swizzled so linear LDS write lands at swizzled position
  int srowA[4], srowB[4], soff[4];
  #pragma unroll
  for (int j = 0; j < 4; ++j) {
    int c = j * 512 + tid;
    int row = c >> 3;
    srowB[j] = nbase + row;
    srowA[j] = min(mbase + row, MPAD - 1);   // clamp pad rows (3168..3199 are zeros)
    soff[j] = ((c & 7) ^ (row & 7)) * 8;     // element offset within row
  }
  const int ldsbase = (tid & 448) * 8;       // wave-uniform: wid*512 elements

  for (int kt = 0; kt < 16; ++kt) {          // BK = 64
    __syncthreads();
    #pragma unroll
    for (int j = 0; j < 4; ++j)
      gload_lds16(H + (size_t)srowA[j] * 1024 + kt * 64 + soff[j],
                  As + j * 4096 + ldsbase);
    #pragma unroll
    for (int j = 0; j < 4; ++j)
      gload_lds16(WT + (size_t)srowB[j] * 1024 + kt * 64 + soff[j],
                  Bs + j * 4096 + ldsbase);
    __syncthreads();                         // drains vmcnt -> LDS ready
    #pragma unroll
    for (int kk = 0; kk < 2; ++kk) {
      const int slot = kk * 4 + kg;
      short8 a[8], b[4];
      #pragma unroll
      for (int m = 0; m < 8; ++m) {
        int r = wm * 128 + m * 16 + (lane & 15);
        a[m] = *(const short8*)&As[r * 64 + ((slot ^ (r & 7)) << 3)];
      }
      #pragma unroll
      for (int n = 0; n < 4; ++n) {
        int r = wn * 64 + n * 16 + (lane & 15);
        b[n] = *(const short8*)&Bs[r * 64 + ((slot ^ (r & 7)) << 3)];
      }
      #pragma unroll
      for (int m = 0; m < 8; ++m)
        #pragma unroll
        for (int n = 0; n < 4; ++n)
          acc[m][n] = __builtin_amdgcn_mfma_f32_16x16x32_bf16(a[m], b[n], acc[m][n], 0, 0, 0);
    }
  }

  #pragma unroll
  for (int n = 0; n < 4; ++n) {
    int gcol = nbase + wn * 64 + n * 16 + (lane & 15);
    float bl = b_lm[gcol];
    #pragma unroll
    for (int m = 0; m < 8; ++m) {
      int rbase = mbase + wm * 128 + m * 16 + ((lane >> 4) << 2);
      #pragma unroll
      for (int q = 0; q < 4; ++q) {
        int r = rbase + q;
        if (r < MROWS)
          out[(size_t)(r + 32) * V_ + gcol] = acc[m][n][q] + bl;
      }
    }
  }
}

extern "C" void kernel_launch(void* const* d_in, const int* in_sizes, int n_in,
                              void* d_out, int out_size, void* d_ws, size_t ws_size,
                              hipStream_t stream) {
  const float* features = (const float*)d_in[0];
  // d_in[1]=W_fk, d_in[2]=b_fk, d_in[5]=W_tk, d_in[6]=b_tk : dead code (softmax over size-1 axis)
  const float* W_fv = (const float*)d_in[3];
  const float* b_fv = (const float*)d_in[4];
  const float* W_ih = (const float*)d_in[7];
  const float* W_hh = (const float*)d_in[8];
  const float* b_ih = (const float*)d_in[9];
  const float* b_hh = (const float*)d_in[10];
  const float* W_lm = (const float*)d_in[11];
  const float* b_lm = (const float*)d_in[12];
  const float* bos  = (const float*)d_in[13];
  float* out = (float*)d_out;
  char* ws = (char*)d_ws;

  __hip_bfloat16* WT   = (__hip_bfloat16*)(ws + OFF_WT);
  __hip_bfloat16* H    = (__hip_bfloat16*)(ws + OFF_H);
  float* fsum          = (float*)(ws + OFF_FSUM);
  float* ctx           = (float*)(ws + OFF_CTX);
  float* gbase         = (float*)(ws + OFF_GBASE);
  unsigned long long* Ex = (unsigned long long*)(ws + OFF_EX);

  hipLaunchKernelGGL(k_first, dim3(4000), dim3(256), 0, stream, out, H);
  hipLaunchKernelGGL(k_fsum,  dim3(128),  dim3(256), 0, stream, features, fsum);
  hipLaunchKernelGGL(k_ctx,   dim3(4, 32),  dim3(256), 0, stream, fsum, W_fv, b_fv, ctx);
  hipLaunchKernelGGL(k_gbase, dim3(16, 4),  dim3(256), 0, stream, ctx, W_ih, b_ih, b_hh, gbase);
  hipLaunchKernelGGL(k_convT, dim3(16, 500), dim3(256), 0, stream, W_lm, WT);
  // Ex aliases fsum+ctx (both dead now); zero tags before k_rec
  hipMemsetAsync(Ex, 0, 262144, stream);
  hipLaunchKernelGGL(k_rec,   dim3(32),   dim3(1024), 147968, stream, gbase, W_hh, bos, H, Ex);
  hipLaunchKernelGGL(k_gemm,  dim3(1625), dim3(512), 0, stream, H, WT, b_lm, out);
}

// Round 7
// 1209.387 us; speedup vs baseline: 2.1488x; 2.1488x over previous
//
#include <hip/hip_runtime.h>
#include <hip/hip_bf16.h>
#include <stdint.h>

typedef __attribute__((ext_vector_type(8))) short short8;
typedef __attribute__((ext_vector_type(4))) float f32x4;

#define B_ 32
#define N_ 196
#define D_ 1024
#define V_ 32000
#define NSTEP 99
#define MROWS 3168   // 99*32
#define MPAD  3200

// workspace layout (bytes)
#define OFF_WT    0ULL          // bf16 [32000][1024]  = 65,536,000 B
#define OFF_H     65536000ULL   // bf16 [3200][1024]   =  6,553,600 B
#define OFF_FSUM  72089600ULL   // f32  [32][1024]     (dead after k_ctx)
#define OFF_CTX   72220672ULL   // f32  [32][1024]     (dead after k_gbase)
#define OFF_EX    72089600ULL   // u64  [2][16384]     = 262,144 B (aliases FSUM+CTX; memset after k_gbase)
#define OFF_GBASE 72351744ULL   // f32  [32][4096]     = 524,288 B

#define AS3 __attribute__((address_space(3)))
#define AS1 __attribute__((address_space(1)))
static __device__ __forceinline__ void gload_lds16(const void* g, void* l) {
  __builtin_amdgcn_global_load_lds((const AS1 uint32_t*)g, (AS3 uint32_t*)l, 16, 0, 0);
}

// ---------------- fsum[b,e] = sum_n relu(features[b,n,e]) ----------------
__global__ void k_fsum(const float* __restrict__ feat, float* __restrict__ fsum) {
  int idx = blockIdx.x * 256 + threadIdx.x;           // 32768
  int b = idx >> 10, e = idx & 1023;
  const float* p = feat + (size_t)b * (N_ * D_) + e;
  float s = 0.f;
  #pragma unroll 4
  for (int n = 0; n < N_; ++n) s += fmaxf(p[(size_t)n * D_], 0.f);
  fsum[idx] = s;
}

// ---------------- ctx[b,d] = fsum[b,:] @ W_fv[:,d] + 196*b_fv[d] ----------------
__global__ void k_ctx(const float* __restrict__ fsum, const float* __restrict__ W_fv,
                      const float* __restrict__ b_fv, float* __restrict__ ctx) {
  __shared__ float fs[1024];
  int b = blockIdx.y;
  int d = blockIdx.x * 256 + threadIdx.x;             // grid.x = 4
  for (int i = threadIdx.x; i < 1024; i += 256) fs[i] = fsum[b * 1024 + i];
  __syncthreads();
  float s = 196.f * b_fv[d];
  #pragma unroll 4
  for (int e = 0; e < 1024; ++e) s = fmaf(fs[e], W_fv[(size_t)e * 1024 + d], s);
  ctx[b * 1024 + d] = s;
}

// ---------------- gbase[b,j] = ctx[b,:] @ W_ih[:,j] + b_ih[j] + b_hh[j] ----------------
__global__ void k_gbase(const float* __restrict__ ctx, const float* __restrict__ W_ih,
                        const float* __restrict__ b_ih, const float* __restrict__ b_hh,
                        float* __restrict__ gbase) {
  __shared__ float cs[8][1024];
  int j = blockIdx.x * 256 + threadIdx.x;             // grid.x = 16 -> 0..4095
  int b0 = blockIdx.y * 8;                            // grid.y = 4
  for (int i = threadIdx.x; i < 8 * 1024; i += 256)
    cs[i >> 10][i & 1023] = ctx[(size_t)(b0 + (i >> 10)) * 1024 + (i & 1023)];
  __syncthreads();
  float bias = b_ih[j] + b_hh[j];
  float acc[8];
  #pragma unroll
  for (int r = 0; r < 8; ++r) acc[r] = bias;
  for (int e = 0; e < 1024; ++e) {
    float w = W_ih[(size_t)e * 4096 + j];
    #pragma unroll
    for (int r = 0; r < 8; ++r) acc[r] = fmaf(cs[r][e], w, acc[r]);
  }
  #pragma unroll
  for (int r = 0; r < 8; ++r) gbase[(size_t)(b0 + r) * 4096 + j] = acc[r];
}

// ---------------- persistent LSTM recurrence (blocks 0..127) + workers (128..255) ----------------
// Recurrence: round-5 validated scheme (650 us): 128 blocks x 8 dims, fence-free tagged-u64
// exchange, parity double-buffer. Workers run CONCURRENTLY on the other 128 CUs:
// out-one-hot, H pad rows zero, W_lm f32 -> WT bf16 transpose-convert.
__global__ __launch_bounds__(256, 1) void k_rec(
    const float* __restrict__ gbase, const float* __restrict__ W_hh,
    const float* __restrict__ bos, __hip_bfloat16* __restrict__ H,
    unsigned long long* __restrict__ Ex,
    const float* __restrict__ W_lm, __hip_bfloat16* __restrict__ WT,
    float* __restrict__ out) {
  extern __shared__ char lds[];
  const int tid = threadIdx.x;
  const int blk = blockIdx.x;

  if (blk >= 128) {
    // ---------- worker blocks ----------
    __hip_bfloat16* t = (__hip_bfloat16*)lds;          // [64][66]
    int wblk = blk - 128;
    for (int idx = wblk * 256 + tid; idx < B_ * V_; idx += 128 * 256)
      out[idx] = ((idx % V_) == 0) ? 1.0f : 0.0f;
    if (wblk < 64) ((uint32_t*)(H + (size_t)MROWS * D_))[wblk * 256 + tid] = 0u;
    int tx = tid & 63, ty = tid >> 6;
    int word = tx & 31, nh = tx >> 5;
    for (int tile = wblk; tile < 8000; tile += 128) {
      int k0 = (tile & 15) * 64;
      int n0 = (tile >> 4) * 64;
      __syncthreads();
      #pragma unroll
      for (int i = 0; i < 16; ++i) {
        int r = i * 4 + ty;
        t[r * 66 + tx] = __float2bfloat16(W_lm[(size_t)(k0 + r) * V_ + n0 + tx]);
      }
      __syncthreads();
      #pragma unroll
      for (int i = 0; i < 8; ++i) {
        int n = i * 8 + ty * 2 + nh;
        uint32_t lo = *(const uint16_t*)&t[2 * word * 66 + n];
        uint32_t hi = *(const uint16_t*)&t[(2 * word + 1) * 66 + n];
        ((uint32_t*)&WT[(size_t)(n0 + n) * 1024 + k0])[word] = lo | (hi << 16);
      }
    }
    return;
  }

  // ---------- recurrence blocks (round-5 verbatim) ----------
  __hip_bfloat16* hbuf = (__hip_bfloat16*)lds;             // [32][1024] bf16 swizzled (64KB)
  __hip_bfloat16* wbuf = (__hip_bfloat16*)(lds + 65536);   // [32cols][1024] bf16 swizzled (64KB, init only)
  float* gex = (float*)(lds + 131072);                     // [32][33] f32 (4.2KB)

  const int d0 = blk * 8;

  // preload W_hh slice (cols: gate g in [0,4), local dim in [0,8)) -> bf16, swizzled
  for (int idx = tid; idx < 32 * 1024; idx += 256) {
    int c = idx & 31;
    int k = idx >> 5;
    int gcol = ((c >> 3) << 10) + d0 + (c & 7);
    float w = W_hh[(size_t)k * 4096 + gcol];
    int off = c * 1024 + ((((k >> 3) ^ (c & 7)) << 3) | (k & 7));
    wbuf[off] = __float2bfloat16(w);
  }
  // h0 = bos broadcast to all batches
  for (int idx = tid; idx < 32 * 1024; idx += 256) {
    int row = idx >> 10;
    int k = idx & 1023;
    int off = row * 1024 + ((((k >> 3) ^ (row & 7)) << 3) | (k & 7));
    hbuf[off] = __float2bfloat16(bos[k]);
  }

  const int tb = tid >> 3;     // batch 0..31
  const int tdl = tid & 7;     // local dim 0..7
  float gb0 = gbase[(size_t)tb * 4096 + 0 * 1024 + d0 + tdl];
  float gb1 = gbase[(size_t)tb * 4096 + 1 * 1024 + d0 + tdl];
  float gb2 = gbase[(size_t)tb * 4096 + 2 * 1024 + d0 + tdl];
  float gb3 = gbase[(size_t)tb * 4096 + 3 * 1024 + d0 + tdl];
  float cst = 0.f;

  const int lane = tid & 63;
  const int wid = tid >> 6;
  const int wm = wid & 1;                 // M(batch) tile
  const int wn = wid >> 1;                // N(col) tile
  const int arow = wm * 16 + (lane & 15);
  const int bcol = wn * 16 + (lane & 15);
  const int kg = lane >> 4;
  const int axor = arow & 7;

  __syncthreads();

  // hoist W_hh B-fragments into registers (32 x short8 = 128 VGPR)
  short8 breg[32];
  #pragma unroll
  for (int kt = 0; kt < 32; ++kt) {
    int ca = kt * 4 + kg;
    breg[kt] = *(const short8*)&wbuf[bcol * 1024 + ((ca ^ (bcol & 7)) << 3)];
  }

  // consumer-side constants: thread handles words g = w*256 + tid
  const int cbatch = (tid >> 2) & 31;
  const int cpair = tid & 3;
  const int chi = tid >> 7;                 // 0/1
  const int cbase = cbatch * 1024 + cpair * 2;
  const int bxor = cbatch & 7;

  for (int t = 0; t < NSTEP; ++t) {
    // gates_local[32b x 32c] = h @ Wslice  (MFMA 16x16x32 bf16, B in regs)
    f32x4 acc0 = {0.f, 0.f, 0.f, 0.f};
    f32x4 acc1 = {0.f, 0.f, 0.f, 0.f};
    #pragma unroll
    for (int kt = 0; kt < 32; kt += 2) {
      int ca = kt * 4 + kg;
      short8 a0 = *(const short8*)&hbuf[arow * 1024 + ((ca ^ axor) << 3)];
      acc0 = __builtin_amdgcn_mfma_f32_16x16x32_bf16(a0, breg[kt], acc0, 0, 0, 0);
      short8 a1 = *(const short8*)&hbuf[arow * 1024 + (((ca + 4) ^ axor) << 3)];
      acc1 = __builtin_amdgcn_mfma_f32_16x16x32_bf16(a1, breg[kt + 1], acc1, 0, 0, 0);
    }
    acc0 = acc0 + acc1;
    {
      int bq = wm * 16 + ((lane >> 4) << 2);
      #pragma unroll
      for (int q = 0; q < 4; ++q) gex[(bq + q) * 33 + bcol] = acc0[q];
    }
    __syncthreads();   // S1: gex written

    float gi = gex[tb * 33 + 0  + tdl] + gb0;
    float gf = gex[tb * 33 + 8  + tdl] + gb1;
    float gg = gex[tb * 33 + 16 + tdl] + gb2;
    float go = gex[tb * 33 + 24 + tdl] + gb3;
    float si = 1.f / (1.f + __expf(-gi));
    float sf = 1.f / (1.f + __expf(-gf));
    float so = 1.f / (1.f + __expf(-go));
    cst = sf * cst + si * tanhf(gg);
    float h = so * tanhf(cst);
    H[(size_t)t * (B_ * D_) + tb * D_ + d0 + tdl] = __float2bfloat16(h);

    // publish h-pair as tagged u64 (fence-free, relaxed agent atomic)
    float hother = __shfl_xor(h, 1);
    if ((tdl & 1) == 0) {
      __hip_bfloat16 p0 = __float2bfloat16(h);
      __hip_bfloat16 p1 = __float2bfloat16(hother);
      uint32_t pk = (uint32_t)*(uint16_t*)&p0 | ((uint32_t)*(uint16_t*)&p1 << 16);
      unsigned long long v = ((unsigned long long)(unsigned)(t + 1) << 32) | pk;
      unsigned long long* dst = Ex + ((t & 1) ? 16384 : 0) + blk * 128 + tb * 4 + (tdl >> 1);
      __hip_atomic_store(dst, v, __ATOMIC_RELAXED, __HIP_MEMORY_SCOPE_AGENT);
    }

    if (t == NSTEP - 1) break;

    // poll all 16384 words (64/thread), idempotent deposit into hbuf
    {
      const unsigned long long want = (unsigned long long)(unsigned)(t + 1);
      const unsigned long long* ExB = Ex + ((t & 1) ? 16384 : 0);
      for (;;) {
        int nready = 0;
        #pragma unroll
        for (int half = 0; half < 2; ++half) {
          unsigned long long v[32];
          #pragma unroll
          for (int j = 0; j < 32; ++j)
            v[j] = __hip_atomic_load(&ExB[(half * 32 + j) * 256 + tid],
                                     __ATOMIC_RELAXED, __HIP_MEMORY_SCOPE_AGENT);
          #pragma unroll
          for (int j = 0; j < 32; ++j) {
            if ((v[j] >> 32) == want) {
              int slice = (half * 32 + j) * 2 + chi;
              *(uint32_t*)&hbuf[cbase + ((slice ^ bxor) << 3)] = (uint32_t)v[j];
              ++nready;
            }
          }
        }
        if (nready == 64) break;
        __builtin_amdgcn_s_sleep(1);
      }
    }
    __syncthreads();   // S2: hbuf fully deposited
  }
}

// ---------------- logits GEMM: 256x256 tiles, 2-phase double-buffered pipeline ----------------
// [3168(+pad),1024] x [1024,32000]; STAGE(next) -> vmcnt(8) -> raw barrier -> compute(cur).
// Raw s_barrier (not __syncthreads) so the compiler can't inject a vmcnt(0) drain (T3/T4).
__global__ __launch_bounds__(512, 1) void k_gemm(
    const __hip_bfloat16* __restrict__ H,    // [3200][1024] (rows 3168..3199 zero)
    const __hip_bfloat16* __restrict__ WT,   // [32000][1024]
    const float* __restrict__ b_lm,
    float* __restrict__ out) {
  extern __shared__ char glds[];
  __hip_bfloat16* As = (__hip_bfloat16*)glds;            // [2][256*64] = 64 KB
  __hip_bfloat16* Bs = (__hip_bfloat16*)(glds + 65536);  // [2][256*64] = 64 KB

  // XCD-bijective remap: nwg = 1625 = 8*203 + 1
  int bid = blockIdx.x;
  int xcd = bid & 7;
  int idx = bid >> 3;
  int wg = (xcd < 1 ? xcd * 204 : 204 + (xcd - 1) * 203) + idx;
  // grouped raster: groups of GM=4 m-tiles, mt fastest within group (13 = 4+4+4+1)
  int group = wg / 500;                       // 0..3
  int u = wg - group * 500;
  int gm = (group == 3) ? 1 : 4;
  int mt = group * 4 + (u % gm);              // 0..12
  int nt = u / gm;                            // 0..124
  const int mbase = mt * 256;
  const int nbase = nt * 256;

  const int tid = threadIdx.x;
  const int lane = tid & 63;
  const int wid = tid >> 6;      // 0..7
  const int wm = wid >> 2;       // 0..1  (M 128-half)
  const int wn = wid & 3;        // 0..3  (N 64-quarter)

  f32x4 acc[8][4];
  #pragma unroll
  for (int m = 0; m < 8; ++m)
    #pragma unroll
    for (int n = 0; n < 4; ++n) acc[m][n] = (f32x4){0.f, 0.f, 0.f, 0.f};

  const int kg = lane >> 4;

  // staging constants: chunk c = j*512 + tid; row = c>>3; slot = c&7;
  // source slot pre-swizzled so linear LDS write lands at swizzled position
  int srowA[4], srowB[4], soff[4];
  #pragma unroll
  for (int j = 0; j < 4; ++j) {
    int c = j * 512 + tid;
    int row = c >> 3;
    srowB[j] = nbase + row;
    srowA[j] = min(mbase + row, MPAD - 1);   // clamp pad rows (3168..3199 are zeros)
    soff[j] = ((c & 7) ^ (row & 7)) * 8;     // element offset within row
  }
  const int ldsbase = (tid & 448) * 8;       // wave-uniform: wid*512 elements

  auto STAGE = [&](int nb, int kt) {
    #pragma unroll
    for (int j = 0; j < 4; ++j)
      gload_lds16(H + (size_t)srowA[j] * 1024 + kt * 64 + soff[j],
                  As + nb * 16384 + j * 4096 + ldsbase);
    #pragma unroll
    for (int j = 0; j < 4; ++j)
      gload_lds16(WT + (size_t)srowB[j] * 1024 + kt * 64 + soff[j],
                  Bs + nb * 16384 + j * 4096 + ldsbase);
  };
  auto COMPUTE = [&](int nb) {
    #pragma unroll
    for (int kk = 0; kk < 2; ++kk) {
      const int slot = kk * 4 + kg;
      short8 a[8], b[4];
      #pragma unroll
      for (int m = 0; m < 8; ++m) {
        int r = wm * 128 + m * 16 + (lane & 15);
        a[m] = *(const short8*)&As[nb * 16384 + r * 64 + ((slot ^ (r & 7)) << 3)];
      }
      #pragma unroll
      for (int n = 0; n < 4; ++n) {
        int r = wn * 64 + n * 16 + (lane & 15);
        b[n] = *(const short8*)&Bs[nb * 16384 + r * 64 + ((slot ^ (r & 7)) << 3)];
      }
      #pragma unroll
      for (int m = 0; m < 8; ++m)
        #pragma unroll
        for (int n = 0; n < 4; ++n)
          acc[m][n] = __builtin_amdgcn_mfma_f32_16x16x32_bf16(a[m], b[n], acc[m][n], 0, 0, 0);
    }
  };

  STAGE(0, 0);
  for (int kt = 0; kt < 15; ++kt) {
    STAGE((kt + 1) & 1, kt + 1);                       // prefetch next K-tile
    asm volatile("s_waitcnt vmcnt(8)" ::: "memory");   // wait cur's 8 loads only
    __builtin_amdgcn_s_barrier();
    __builtin_amdgcn_sched_barrier(0);
    COMPUTE(kt & 1);
    __builtin_amdgcn_sched_barrier(0);
    __builtin_amdgcn_s_barrier();                      // reads done before overwrite
  }
  asm volatile("s_waitcnt vmcnt(0)" ::: "memory");
  __builtin_amdgcn_s_barrier();
  __builtin_amdgcn_sched_barrier(0);
  COMPUTE(1);

  #pragma unroll
  for (int n = 0; n < 4; ++n) {
    int gcol = nbase + wn * 64 + n * 16 + (lane & 15);
    float bl = b_lm[gcol];
    #pragma unroll
    for (int m = 0; m < 8; ++m) {
      int rbase = mbase + wm * 128 + m * 16 + ((lane >> 4) << 2);
      #pragma unroll
      for (int q = 0; q < 4; ++q) {
        int r = rbase + q;
        if (r < MROWS)
          out[(size_t)(r + 32) * V_ + gcol] = acc[m][n][q] + bl;
      }
    }
  }
}

extern "C" void kernel_launch(void* const* d_in, const int* in_sizes, int n_in,
                              void* d_out, int out_size, void* d_ws, size_t ws_size,
                              hipStream_t stream) {
  const float* features = (const float*)d_in[0];
  // d_in[1]=W_fk, d_in[2]=b_fk, d_in[5]=W_tk, d_in[6]=b_tk : dead code (softmax over size-1 axis)
  const float* W_fv = (const float*)d_in[3];
  const float* b_fv = (const float*)d_in[4];
  const float* W_ih = (const float*)d_in[7];
  const float* W_hh = (const float*)d_in[8];
  const float* b_ih = (const float*)d_in[9];
  const float* b_hh = (const float*)d_in[10];
  const float* W_lm = (const float*)d_in[11];
  const float* b_lm = (const float*)d_in[12];
  const float* bos  = (const float*)d_in[13];
  float* out = (float*)d_out;
  char* ws = (char*)d_ws;

  __hip_bfloat16* WT   = (__hip_bfloat16*)(ws + OFF_WT);
  __hip_bfloat16* H    = (__hip_bfloat16*)(ws + OFF_H);
  float* fsum          = (float*)(ws + OFF_FSUM);
  float* ctx           = (float*)(ws + OFF_CTX);
  float* gbase         = (float*)(ws + OFF_GBASE);
  unsigned long long* Ex = (unsigned long long*)(ws + OFF_EX);

  hipLaunchKernelGGL(k_fsum,  dim3(128),  dim3(256), 0, stream, features, fsum);
  hipLaunchKernelGGL(k_ctx,   dim3(4, 32),  dim3(256), 0, stream, fsum, W_fv, b_fv, ctx);
  hipLaunchKernelGGL(k_gbase, dim3(16, 4),  dim3(256), 0, stream, ctx, W_ih, b_ih, b_hh, gbase);
  // Ex aliases fsum+ctx (both dead now); zero tags before k_rec
  hipMemsetAsync(Ex, 0, 262144, stream);
  // blocks 0..127: recurrence; blocks 128..255: out-one-hot + H pad + W_lm->WT (concurrent)
  hipLaunchKernelGGL(k_rec,   dim3(256),  dim3(256), 135296, stream,
                     gbase, W_hh, bos, H, Ex, W_lm, WT, out);
  hipLaunchKernelGGL(k_gemm,  dim3(1625), dim3(512), 131072, stream, H, WT, b_lm, out);
}